// Round 8
// baseline (137.965 us; speedup 1.0000x reference)
//
#include <hip/hip_runtime.h>

// Chamfer distance via MFMA: d_ij = |p|^2 + |t|^2 - 2 p.t packed into ONE
// v_mfma_f32_32x32x16_bf16 per 32x32 tile using K-slot packing (K=16):
//   coord c (x,y,z): A slots [ch,ch,cl,cl], B slots [qh,ql,qh,ql], q = -2t
//     -> (ch+cl)*(qh+ql) = -2 c_p * c_t  (exact products: bf16*bf16 fits fp32)
//   norms: A [n2h,n2l,1,1], B [1,1,n2h,n2l] -> |p|^2 + |t|^2
// hi/lo bf16 split gives ~16-bit effective mantissa -> |err| ~3e-5 << 6e-4 thr.
//
// v10: one-pass (rows=predict, cols=target; dist1=row-min, dist2=col-min)
// with v9's two bugs fixed:
//  - col-min: lg-split LDS (cm[w][lg*1024 + t*32 + lm], all 64 lanes write,
//    no in-loop shfl/bpermute, no lane<32 divergence); balanced register
//    tree with compile-time indices.
//  - reduce kernel REMOVED: v4-verified clamped-bits atomicMin for rows
//    (contention 16) and cols (contention 64) + ticket + last-block sum of
//    2N floats (128 KB). 2-kernel chain.
// Regalloc ledger: launch_bounds(256,2) (v3-proven), 2 strips + 2 bufs.

typedef short s16x8 __attribute__((ext_vector_type(8)));
typedef float f32x16 __attribute__((ext_vector_type(16)));

static __device__ __forceinline__ unsigned short f2bf(float f) {
    unsigned u = __float_as_uint(f);
    unsigned r = (u + 0x7FFFu + ((u >> 16) & 1u)) >> 16;  // RNE
    return (unsigned short)r;
}
static __device__ __forceinline__ float bf2f(unsigned short h) {
    return __uint_as_float(((unsigned)h) << 16);
}
static __device__ __forceinline__ void split2(float v, unsigned short& h, unsigned short& l) {
    h = f2bf(v);
    l = f2bf(v - bf2f(h));
}
// Min over the 32 values {p[0..15], q[0..15]} (one column's 32 rows held by
// this lane across two row-strips). Balanced tree, compile-time indices.
static __device__ __forceinline__ float colmin32(f32x16 p, f32x16 q) {
    float v[32];
    #pragma unroll
    for (int r = 0; r < 16; ++r) { v[r] = p[r]; v[16 + r] = q[r]; }
    #pragma unroll
    for (int s = 16; s >= 1; s >>= 1) {
        #pragma unroll
        for (int i = 0; i < s; ++i) v[i] = fminf(v[i], v[i + s]);
    }
    return v[0];
}

union Pack16 { unsigned short u[16]; uint4 v[2]; };

#define CG 16   // column groups (N/CG = 1024 cols per block)

// Build A-pack (predict) and B-pack (target); init minbits[2N] + ticket.
__global__ void prep_pack(const float* __restrict__ predict, const float* __restrict__ target,
                          unsigned short* __restrict__ ApP, unsigned short* __restrict__ BpT,
                          unsigned* __restrict__ minbits, unsigned* __restrict__ ticket,
                          int N)
{
    int i = blockIdx.x * blockDim.x + threadIdx.x;
    if (i == 0) *ticket = 0u;
    if (i >= 2 * N) return;
    minbits[i] = 0x7F7FFFFFu;   // FLT_MAX bits (all stored mins are >= 0)
    const unsigned short one = f2bf(1.0f);

    if (i < N) {                 // predict -> A pack
        float x = predict[3*i], y = predict[3*i+1], z = predict[3*i+2];
        float n2 = __builtin_fmaf(x, x, __builtin_fmaf(y, y, z*z));
        unsigned short xh,xl,yh,yl,zh,zl,nh,nl;
        split2(x, xh, xl); split2(y, yh, yl); split2(z, zh, zl); split2(n2, nh, nl);
        Pack16 a;
        a.u[0]=xh; a.u[1]=xh; a.u[2]=xl; a.u[3]=xl;
        a.u[4]=yh; a.u[5]=yh; a.u[6]=yl; a.u[7]=yl;
        a.u[8]=zh; a.u[9]=zh; a.u[10]=zl; a.u[11]=zl;
        a.u[12]=nh; a.u[13]=nl; a.u[14]=one; a.u[15]=one;
        uint4* ad = (uint4*)(ApP + (size_t)i * 16);
        ad[0] = a.v[0]; ad[1] = a.v[1];
    } else {                     // target -> B pack
        int j = i - N;
        float x = target[3*j], y = target[3*j+1], z = target[3*j+2];
        float n2 = __builtin_fmaf(x, x, __builtin_fmaf(y, y, z*z));
        unsigned short nh,nl,qxh,qxl,qyh,qyl,qzh,qzl;
        split2(n2, nh, nl);
        split2(-2.0f*x, qxh, qxl); split2(-2.0f*y, qyh, qyl); split2(-2.0f*z, qzh, qzl);
        Pack16 b;
        b.u[0]=qxh; b.u[1]=qxl; b.u[2]=qxh; b.u[3]=qxl;
        b.u[4]=qyh; b.u[5]=qyl; b.u[6]=qyh; b.u[7]=qyl;
        b.u[8]=qzh; b.u[9]=qzl; b.u[10]=qzh; b.u[11]=qzl;
        b.u[12]=one; b.u[13]=one; b.u[14]=nh; b.u[15]=nl;
        uint4* bd = (uint4*)(BpT + (size_t)j * 16);
        bd[0] = b.v[0]; bd[1] = b.v[1];
    }
}

// Block: 256 threads (4 waves). Each wave owns 64 rows (2 strips of 32).
// Block covers predict rows [bx*256,+256) x target cols [cg*1024,+1024).
// Per 32x32 tile: row-min into registers; col-min (this lane's 32 rows of
// col lm, half lg) into per-wave lg-split LDS strip. Epilogue: row shuffle
// reduce + atomicMin; cross-wave col fold + atomicMin; ticket; last block
// sums minbits[2N] and writes the mean.
__global__ __launch_bounds__(256, 2) void chamfer_main(
    const unsigned short* __restrict__ Ap, const unsigned short* __restrict__ Bp,
    unsigned* __restrict__ minbits, unsigned* __restrict__ ticket,
    float* __restrict__ out, int N)
{
    __shared__ float cm[4][2048];   // [wave][lg*1024 + col] : 32 KB

    const int tid  = threadIdx.x;
    const int w    = tid >> 6;
    const int lane = tid & 63;
    const int lm   = lane & 31;     // MFMA row/col within tile
    const int lg   = lane >> 5;     // k-half (and C/D row-half)
    const int bx   = blockIdx.x;
    const int cg   = blockIdx.y;

    const int row0 = bx * 256 + w * 64;

    // A fragments (hoisted for the whole kernel): lane needs A[row][k=lg*8..+7]
    const uint4* A4 = (const uint4*)Ap;
    s16x8 a0 = __builtin_bit_cast(s16x8, A4[(size_t)(row0      + lm) * 2 + lg]);
    s16x8 a1 = __builtin_bit_cast(s16x8, A4[(size_t)(row0 + 32 + lm) * 2 + lg]);

    float rm0[16], rm1[16];
    #pragma unroll
    for (int r = 0; r < 16; ++r) { rm0[r] = 3.0e38f; rm1[r] = 3.0e38f; }

    const f32x16 zc = {0.f,0.f,0.f,0.f,0.f,0.f,0.f,0.f,0.f,0.f,0.f,0.f,0.f,0.f,0.f,0.f};

    const int npt = N / CG;               // 1024 cols per block
    const int NT  = npt / 32;             // 32 tiles
    const uint4* bp = (const uint4*)Bp + (size_t)cg * npt * 2 + lm * 2 + lg;
    float* cmw = cm[w] + lg * 1024;       // this lane-half's strip

    // Register double-buffer over PAIRS of tiles (stride per tile = 64 uint4).
    uint4 c0 = bp[0];
    uint4 c1 = bp[64];
    const uint4* bnext = bp + 128;

#define BODY(TT)                                                              \
    {                                                                         \
        s16x8 bA = __builtin_bit_cast(s16x8, c0);                             \
        s16x8 bB = __builtin_bit_cast(s16x8, c1);                             \
        f32x16 p0 = __builtin_amdgcn_mfma_f32_32x32x16_bf16(a0, bA, zc, 0,0,0);\
        f32x16 q0 = __builtin_amdgcn_mfma_f32_32x32x16_bf16(a0, bB, zc, 0,0,0);\
        f32x16 p1 = __builtin_amdgcn_mfma_f32_32x32x16_bf16(a1, bA, zc, 0,0,0);\
        f32x16 q1 = __builtin_amdgcn_mfma_f32_32x32x16_bf16(a1, bB, zc, 0,0,0);\
        _Pragma("unroll")                                                     \
        for (int r = 0; r < 16; ++r) {                                        \
            rm0[r] = fminf(fminf(rm0[r], p0[r]), q0[r]);                      \
            rm1[r] = fminf(fminf(rm1[r], p1[r]), q1[r]);                      \
        }                                                                     \
        cmw[(TT) * 32 + lm]     = colmin32(p0, p1);                           \
        cmw[(TT + 1) * 32 + lm] = colmin32(q0, q1);                           \
    }

    int t = 0;
    for (; t < NT - 2; t += 2) {
        uint4 n0 = bnext[0];
        uint4 n1 = bnext[64];
        bnext += 128;
        BODY(t);
        c0 = n0; c1 = n1;
    }
    BODY(t);   // last pair, t == NT-2
#undef BODY

    // dist1: reduce row-mins across the 32 col-lanes of each half.
    #pragma unroll
    for (int m = 1; m <= 16; m <<= 1) {
        #pragma unroll
        for (int r = 0; r < 16; ++r) {
            rm0[r] = fminf(rm0[r], __shfl_xor(rm0[r], m, 64));
            rm1[r] = fminf(rm1[r], __shfl_xor(rm1[r], m, 64));
        }
    }
    // C/D layout (m74/m101): row = (r&3) + 8*(r>>2) + 4*lg, col = lane&31.
    // Clamp at 0, atomicMin on bit pattern (exact for non-negative floats).
    #pragma unroll
    for (int r = 0; r < 16; ++r) {
        int rl = (r & 3) + 8 * (r >> 2) + 4 * lg;
        if (lm == r) {
            atomicMin(&minbits[row0 +      rl], __float_as_uint(fmaxf(rm0[r], 0.0f)));
            atomicMin(&minbits[row0 + 32 + rl], __float_as_uint(fmaxf(rm1[r], 0.0f)));
        }
    }

    // dist2: fold the 4 waves x 2 halves per col, atomicMin to global col.
    __syncthreads();
    unsigned* __restrict__ cbits = minbits + N + (size_t)cg * npt;
    for (int c = tid; c < npt; c += 256) {
        float m = fminf(fminf(fminf(cm[0][c], cm[0][1024 + c]),
                              fminf(cm[1][c], cm[1][1024 + c])),
                        fminf(fminf(cm[2][c], cm[2][1024 + c]),
                              fminf(cm[3][c], cm[3][1024 + c])));
        atomicMin(&cbits[c], __float_as_uint(fmaxf(m, 0.0f)));
    }

    // Last-block ticket: final sum over rows (dist1) + cols (dist2).
    __threadfence();
    __shared__ unsigned is_last;
    if (tid == 0) {
        unsigned total = gridDim.x * gridDim.y;
        unsigned old = atomicAdd(ticket, 1u);
        is_last = (old == total - 1u) ? 1u : 0u;
    }
    __syncthreads();
    if (!is_last) return;
    __threadfence();   // acquire: other blocks' atomicMin results

    const uint4* mb4 = (const uint4*)minbits;
    const int n4 = (2 * N) >> 2;   // 8192
    double acc = 0.0;
    #pragma unroll 4
    for (int i = tid; i < n4; i += 256) {
        uint4 v = mb4[i];
        acc += (double)__uint_as_float(v.x) + (double)__uint_as_float(v.y)
             + (double)__uint_as_float(v.z) + (double)__uint_as_float(v.w);
    }
    for (int off = 32; off; off >>= 1)
        acc += __shfl_down(acc, off, 64);
    __shared__ double sacc[4];
    if (lane == 0) sacc[w] = acc;
    __syncthreads();
    if (tid == 0)
        out[0] = (float)((sacc[0] + sacc[1] + sacc[2] + sacc[3]) / (double)N);
}

extern "C" void kernel_launch(void* const* d_in, const int* in_sizes, int n_in,
                              void* d_out, int out_size, void* d_ws, size_t ws_size,
                              hipStream_t stream) {
    const float* predict = (const float*)d_in[0];
    const float* target  = (const float*)d_in[1];
    const int N = in_sizes[0] / 3;   // 16384

    unsigned short* ws16 = (unsigned short*)d_ws;
    unsigned short* ApP = ws16;                                   // N*16 bf16
    unsigned short* BpT = ws16 + (size_t)1 * N * 16;              // N*16 bf16
    unsigned* minbits = (unsigned*)(ws16 + (size_t)2 * N * 16);   // 2N uints
    unsigned* ticket  = minbits + (size_t)2 * N;                  // 1 uint

    prep_pack<<<dim3((2 * N + 255) / 256), dim3(256), 0, stream>>>(
        predict, target, ApP, BpT, minbits, ticket, N);

    dim3 grid(N / 256, CG);   // 64 x 16 = 1024 blocks
    chamfer_main<<<grid, dim3(256), 0, stream>>>(
        ApP, BpT, minbits, ticket, (float*)d_out, N);
}

// Round 9
// 83.844 us; speedup vs baseline: 1.6455x; 1.6455x over previous
//
#include <hip/hip_runtime.h>

// Chamfer distance via MFMA: d_ij = |p|^2 + |t|^2 - 2 p.t packed into ONE
// v_mfma_f32_32x32x16_bf16 per 32x32 tile using K-slot packing (K=16):
//   coord c (x,y,z): A slots [ch,ch,cl,cl], B slots [qh,ql,qh,ql], q = -2t
//     -> (ch+cl)*(qh+ql) = -2 c_p * c_t  (exact products: bf16*bf16 fits fp32)
//   norms: A [n2h,n2l,1,1], B [1,1,n2h,n2l] -> |p|^2 + |t|^2
// hi/lo bf16 split gives ~16-bit effective mantissa -> |err| ~3e-5 << 6e-4 thr.
//
// FINAL (= v5, session best 82.9 us): no-LDS main (B fragments direct from
// L2, register double-buffer over tile pairs), fminf-chain min updates,
// launch_bounds(256,4), 8 col-groups, two-stage parallel reduce.
//
// Session ledger (why this exact shape):
//  - v2 inline-asm v_min3_f32: miscompiled (1.2% loss error) -> fminf only.
//  - v4 quad-prefetch (8 bufs): regalloc collapse VGPR=56, 94 us main.
//  - v7 4 row-strips/wave:      regalloc collapse VGPR=76, 62 us main.
//  - v9/v10 one-pass col-min:   regalloc collapse again, 93/138 us total.
//  => NEVER exceed 2 strips + 2 prefetch bufs of per-wave state; never fuse
//     extra phases into chamfer_main. The loop body below is codegen-proven.
//  - Measured window = ~41 us harness ws-poison fill (immovable) + ~9 us
//    prep/reduce/gaps + ~30 us main (resists LDS/occupancy/prefetch levers).

typedef short s16x8 __attribute__((ext_vector_type(8)));
typedef float f32x16 __attribute__((ext_vector_type(16)));

static __device__ __forceinline__ unsigned short f2bf(float f) {
    unsigned u = __float_as_uint(f);
    unsigned r = (u + 0x7FFFu + ((u >> 16) & 1u)) >> 16;  // RNE
    return (unsigned short)r;
}
static __device__ __forceinline__ float bf2f(unsigned short h) {
    return __uint_as_float(((unsigned)h) << 16);
}
static __device__ __forceinline__ void split2(float v, unsigned short& h, unsigned short& l) {
    h = f2bf(v);
    l = f2bf(v - bf2f(h));
}

union Pack16 { unsigned short u[16]; uint4 v[2]; };

// Build A-operand pack (own coords, own n2) and B-operand pack (-2*coords, own n2)
// for every point of both clouds. Layout: [point][16] bf16, 32 B per point.
__global__ void prep_pack(const float* __restrict__ predict, const float* __restrict__ target,
                          unsigned short* __restrict__ ApP, unsigned short* __restrict__ BpP,
                          unsigned short* __restrict__ ApT, unsigned short* __restrict__ BpT,
                          int N)
{
    int i = blockIdx.x * blockDim.x + threadIdx.x;
    if (i >= 2 * N) return;
    const float* src = (i < N) ? predict : target;
    unsigned short* Ap = (i < N) ? ApP : ApT;
    unsigned short* Bp = (i < N) ? BpP : BpT;
    int j = (i < N) ? i : i - N;

    float x = src[3*j], y = src[3*j+1], z = src[3*j+2];
    float n2 = __builtin_fmaf(x, x, __builtin_fmaf(y, y, z*z));

    unsigned short xh,xl,yh,yl,zh,zl,nh,nl,qxh,qxl,qyh,qyl,qzh,qzl;
    split2(x, xh, xl); split2(y, yh, yl); split2(z, zh, zl); split2(n2, nh, nl);
    split2(-2.0f*x, qxh, qxl); split2(-2.0f*y, qyh, qyl); split2(-2.0f*z, qzh, qzl);
    const unsigned short one = f2bf(1.0f);

    Pack16 a, b;
    a.u[0]=xh; a.u[1]=xh; a.u[2]=xl; a.u[3]=xl;
    a.u[4]=yh; a.u[5]=yh; a.u[6]=yl; a.u[7]=yl;
    a.u[8]=zh; a.u[9]=zh; a.u[10]=zl; a.u[11]=zl;
    a.u[12]=nh; a.u[13]=nl; a.u[14]=one; a.u[15]=one;

    b.u[0]=qxh; b.u[1]=qxl; b.u[2]=qxh; b.u[3]=qxl;
    b.u[4]=qyh; b.u[5]=qyl; b.u[6]=qyh; b.u[7]=qyl;
    b.u[8]=qzh; b.u[9]=qzl; b.u[10]=qzh; b.u[11]=qzl;
    b.u[12]=one; b.u[13]=one; b.u[14]=nh; b.u[15]=nl;

    uint4* ad = (uint4*)(Ap + (size_t)j * 16);
    uint4* bd = (uint4*)(Bp + (size_t)j * 16);
    ad[0] = a.v[0]; ad[1] = a.v[1];
    bd[0] = b.v[0]; bd[1] = b.v[1];
}

#define CG 8   // column groups per direction

// Block: 256 threads (4 waves). Each wave owns 64 rows (2 strips of 32).
// Block covers rows [bx*256, +256), col-group blockIdx.y (N/CG cols), dir z.
// No LDS: B fragments come straight from L2 (total B data = 1 MB, resident).
__global__ __launch_bounds__(256, 4) void chamfer_main(
    const unsigned short* __restrict__ ApP, const unsigned short* __restrict__ BpP,
    const unsigned short* __restrict__ ApT, const unsigned short* __restrict__ BpT,
    float* __restrict__ partials, int N)
{
    const int dir = blockIdx.z;
    const unsigned short* __restrict__ Ap = dir ? ApT : ApP;
    const unsigned short* __restrict__ Bp = dir ? BpP : BpT;
    float* __restrict__ pout = partials + (size_t)(dir * CG + blockIdx.y) * N;

    const int tid  = threadIdx.x;
    const int w    = tid >> 6;
    const int lane = tid & 63;
    const int lm   = lane & 31;     // MFMA row/col within tile
    const int lg   = lane >> 5;     // k-half (and C/D row-half)

    const int row0 = blockIdx.x * 256 + w * 64;

    // A fragments (hoisted for the whole kernel): lane needs A[row][k=lg*8..+7]
    const uint4* A4 = (const uint4*)Ap;
    s16x8 a0 = __builtin_bit_cast(s16x8, A4[(size_t)(row0      + lm) * 2 + lg]);
    s16x8 a1 = __builtin_bit_cast(s16x8, A4[(size_t)(row0 + 32 + lm) * 2 + lg]);

    float rm0[16], rm1[16];
    #pragma unroll
    for (int r = 0; r < 16; ++r) { rm0[r] = 3.0e38f; rm1[r] = 3.0e38f; }

    const f32x16 zc = {0.f,0.f,0.f,0.f,0.f,0.f,0.f,0.f,0.f,0.f,0.f,0.f,0.f,0.f,0.f,0.f};

    // This block's B slice: N/CG cols. Per-lane fragment address:
    // tile t, col lm, k-half lg -> uint4 index t*64 + lm*2 + lg (32 B/point).
    const int npt = N / CG;
    const int NT  = npt / 32;             // 64 tiles for N=16384, CG=8
    const uint4* bp = (const uint4*)Bp + (size_t)blockIdx.y * npt * 2 + lm * 2 + lg;

    // Register double-buffer over PAIRS of tiles (stride per tile = 64 uint4).
    uint4 c0 = bp[0];
    uint4 c1 = bp[64];
    const uint4* bnext = bp + 128;

    for (int t = 0; t < NT - 2; t += 2) {
        uint4 n0 = bnext[0];
        uint4 n1 = bnext[64];
        bnext += 128;
        s16x8 bA = __builtin_bit_cast(s16x8, c0);
        s16x8 bB = __builtin_bit_cast(s16x8, c1);
        f32x16 p0 = __builtin_amdgcn_mfma_f32_32x32x16_bf16(a0, bA, zc, 0, 0, 0);
        f32x16 q0 = __builtin_amdgcn_mfma_f32_32x32x16_bf16(a0, bB, zc, 0, 0, 0);
        f32x16 p1 = __builtin_amdgcn_mfma_f32_32x32x16_bf16(a1, bA, zc, 0, 0, 0);
        f32x16 q1 = __builtin_amdgcn_mfma_f32_32x32x16_bf16(a1, bB, zc, 0, 0, 0);
        #pragma unroll
        for (int r = 0; r < 16; ++r) {
            rm0[r] = fminf(fminf(rm0[r], p0[r]), q0[r]);
            rm1[r] = fminf(fminf(rm1[r], p1[r]), q1[r]);
        }
        c0 = n0; c1 = n1;
    }
    {   // last pair (no prefetch)
        s16x8 bA = __builtin_bit_cast(s16x8, c0);
        s16x8 bB = __builtin_bit_cast(s16x8, c1);
        f32x16 p0 = __builtin_amdgcn_mfma_f32_32x32x16_bf16(a0, bA, zc, 0, 0, 0);
        f32x16 q0 = __builtin_amdgcn_mfma_f32_32x32x16_bf16(a0, bB, zc, 0, 0, 0);
        f32x16 p1 = __builtin_amdgcn_mfma_f32_32x32x16_bf16(a1, bA, zc, 0, 0, 0);
        f32x16 q1 = __builtin_amdgcn_mfma_f32_32x32x16_bf16(a1, bB, zc, 0, 0, 0);
        #pragma unroll
        for (int r = 0; r < 16; ++r) {
            rm0[r] = fminf(fminf(rm0[r], p0[r]), q0[r]);
            rm1[r] = fminf(fminf(rm1[r], p1[r]), q1[r]);
        }
    }

    // Reduce row-mins across the 32 col-lanes of each half (xor stays in-half).
    #pragma unroll
    for (int m = 1; m <= 16; m <<= 1) {
        #pragma unroll
        for (int r = 0; r < 16; ++r) {
            rm0[r] = fminf(rm0[r], __shfl_xor(rm0[r], m, 64));
            rm1[r] = fminf(rm1[r], __shfl_xor(rm1[r], m, 64));
        }
    }
    // C/D layout (m74/m101): row = (r&3) + 8*(r>>2) + 4*lg, col = lane&31.
    #pragma unroll
    for (int r = 0; r < 16; ++r) {
        int rl = (r & 3) + 8 * (r >> 2) + 4 * lg;
        if (lm == r) {
            pout[row0 +      rl] = rm0[r];
            pout[row0 + 32 + rl] = rm1[r];
        }
    }
}

// Stage 1: 16 blocks x 256 threads, float4-vectorized min over the 2*CG
// partial arrays, clamp at 0, per-block double sum.
__global__ void chamfer_reduce1(const float* __restrict__ partials,
                                double* __restrict__ bsum, int N)
{
    const int n4 = N >> 2;
    const float4* p4 = (const float4*)partials;
    double acc = 0.0;
    for (int i = blockIdx.x * blockDim.x + threadIdx.x; i < n4;
         i += gridDim.x * blockDim.x) {
        float4 m0 = p4[i];
        #pragma unroll
        for (int g = 1; g < CG; ++g) {
            float4 v = p4[(size_t)g * n4 + i];
            m0.x = fminf(m0.x, v.x); m0.y = fminf(m0.y, v.y);
            m0.z = fminf(m0.z, v.z); m0.w = fminf(m0.w, v.w);
        }
        float4 m1 = p4[(size_t)CG * n4 + i];
        #pragma unroll
        for (int g = CG + 1; g < 2 * CG; ++g) {
            float4 v = p4[(size_t)g * n4 + i];
            m1.x = fminf(m1.x, v.x); m1.y = fminf(m1.y, v.y);
            m1.z = fminf(m1.z, v.z); m1.w = fminf(m1.w, v.w);
        }
        acc += (double)fmaxf(m0.x, 0.0f) + (double)fmaxf(m0.y, 0.0f)
             + (double)fmaxf(m0.z, 0.0f) + (double)fmaxf(m0.w, 0.0f)
             + (double)fmaxf(m1.x, 0.0f) + (double)fmaxf(m1.y, 0.0f)
             + (double)fmaxf(m1.z, 0.0f) + (double)fmaxf(m1.w, 0.0f);
    }
    for (int off = 32; off; off >>= 1)
        acc += __shfl_down(acc, off, 64);
    __shared__ double sacc[4];
    const int wave = threadIdx.x >> 6, lane = threadIdx.x & 63;
    if (lane == 0) sacc[wave] = acc;
    __syncthreads();
    if (threadIdx.x == 0)
        bsum[blockIdx.x] = sacc[0] + sacc[1] + sacc[2] + sacc[3];
}

// Stage 2: fold 16 block sums, write mean(dist1)+mean(dist2).
__global__ void chamfer_reduce2(const double* __restrict__ bsum,
                                float* __restrict__ out, int N, int nb)
{
    if (threadIdx.x == 0) {
        double t = 0.0;
        for (int i = 0; i < nb; ++i) t += bsum[i];
        out[0] = (float)(t / (double)N);   // N == M
    }
}

extern "C" void kernel_launch(void* const* d_in, const int* in_sizes, int n_in,
                              void* d_out, int out_size, void* d_ws, size_t ws_size,
                              hipStream_t stream) {
    const float* predict = (const float*)d_in[0];
    const float* target  = (const float*)d_in[1];
    const int N = in_sizes[0] / 3;   // 16384

    unsigned short* ws16 = (unsigned short*)d_ws;
    unsigned short* ApP = ws16;
    unsigned short* BpP = ws16 + (size_t)1 * N * 16;
    unsigned short* ApT = ws16 + (size_t)2 * N * 16;
    unsigned short* BpT = ws16 + (size_t)3 * N * 16;
    float* partials = (float*)(ws16 + (size_t)4 * N * 16);   // 2*CG*N floats
    double* bsum = (double*)(partials + (size_t)2 * CG * N); // 16 doubles

    prep_pack<<<dim3((2 * N + 255) / 256), dim3(256), 0, stream>>>(
        predict, target, ApP, BpP, ApT, BpT, N);

    dim3 grid(N / 256, CG, 2);   // 64 x 8 x 2 = 1024 blocks
    chamfer_main<<<grid, dim3(256), 0, stream>>>(ApP, BpP, ApT, BpT, partials, N);

    chamfer_reduce1<<<dim3(16), dim3(256), 0, stream>>>(partials, bsum, N);
    chamfer_reduce2<<<dim3(1), dim3(64), 0, stream>>>(bsum, (float*)d_out, N, 16);
}

// Round 10
// 82.286 us; speedup vs baseline: 1.6766x; 1.0189x over previous
//
#include <hip/hip_runtime.h>

// Chamfer distance via MFMA: d_ij = |p|^2 + |t|^2 - 2 p.t packed into ONE
// v_mfma_f32_32x32x16_bf16 per 32x32 tile using K-slot packing (K=16):
//   coord c (x,y,z): A slots [ch,ch,cl,cl], B slots [qh,ql,qh,ql], q = -2t
//     -> (ch+cl)*(qh+ql) = -2 c_p * c_t  (exact products: bf16*bf16 fits fp32)
//   norms: A [n2h,n2l,1,1], B [1,1,n2h,n2l] -> |p|^2 + |t|^2
// hi/lo bf16 split gives ~16-bit effective mantissa -> |err| ~3e-5 << 6e-4 thr.
//
// v11: v5 with ONE controlled change: depth-2 (quad-buffer) prefetch in the
// main loop, launch_bounds(256,2), per-pair interleaved MFMA->min (<=2
// f32x16 transients), next-quad loads issued in two halves. Reduce kernels
// byte-identical to v5 (separate; NO fused ticket epilogue).
// Ledger note: the three regalloc collapses (v4/v7/v10, VGPR 56/76/60) all
// carried the fused last-block epilogue; this is the first epilogue-free
// deep-prefetch test. If it also collapses, quad prefetch itself is the
// trigger and v5 is the final answer.

typedef short s16x8 __attribute__((ext_vector_type(8)));
typedef float f32x16 __attribute__((ext_vector_type(16)));

static __device__ __forceinline__ unsigned short f2bf(float f) {
    unsigned u = __float_as_uint(f);
    unsigned r = (u + 0x7FFFu + ((u >> 16) & 1u)) >> 16;  // RNE
    return (unsigned short)r;
}
static __device__ __forceinline__ float bf2f(unsigned short h) {
    return __uint_as_float(((unsigned)h) << 16);
}
static __device__ __forceinline__ void split2(float v, unsigned short& h, unsigned short& l) {
    h = f2bf(v);
    l = f2bf(v - bf2f(h));
}

union Pack16 { unsigned short u[16]; uint4 v[2]; };

// Build A-operand pack (own coords, own n2) and B-operand pack (-2*coords, own n2)
// for every point of both clouds. Layout: [point][16] bf16, 32 B per point.
__global__ void prep_pack(const float* __restrict__ predict, const float* __restrict__ target,
                          unsigned short* __restrict__ ApP, unsigned short* __restrict__ BpP,
                          unsigned short* __restrict__ ApT, unsigned short* __restrict__ BpT,
                          int N)
{
    int i = blockIdx.x * blockDim.x + threadIdx.x;
    if (i >= 2 * N) return;
    const float* src = (i < N) ? predict : target;
    unsigned short* Ap = (i < N) ? ApP : ApT;
    unsigned short* Bp = (i < N) ? BpP : BpT;
    int j = (i < N) ? i : i - N;

    float x = src[3*j], y = src[3*j+1], z = src[3*j+2];
    float n2 = __builtin_fmaf(x, x, __builtin_fmaf(y, y, z*z));

    unsigned short xh,xl,yh,yl,zh,zl,nh,nl,qxh,qxl,qyh,qyl,qzh,qzl;
    split2(x, xh, xl); split2(y, yh, yl); split2(z, zh, zl); split2(n2, nh, nl);
    split2(-2.0f*x, qxh, qxl); split2(-2.0f*y, qyh, qyl); split2(-2.0f*z, qzh, qzl);
    const unsigned short one = f2bf(1.0f);

    Pack16 a, b;
    a.u[0]=xh; a.u[1]=xh; a.u[2]=xl; a.u[3]=xl;
    a.u[4]=yh; a.u[5]=yh; a.u[6]=yl; a.u[7]=yl;
    a.u[8]=zh; a.u[9]=zh; a.u[10]=zl; a.u[11]=zl;
    a.u[12]=nh; a.u[13]=nl; a.u[14]=one; a.u[15]=one;

    b.u[0]=qxh; b.u[1]=qxl; b.u[2]=qxh; b.u[3]=qxl;
    b.u[4]=qyh; b.u[5]=qyl; b.u[6]=qyh; b.u[7]=qyl;
    b.u[8]=qzh; b.u[9]=qzl; b.u[10]=qzh; b.u[11]=qzl;
    b.u[12]=one; b.u[13]=one; b.u[14]=nh; b.u[15]=nl;

    uint4* ad = (uint4*)(Ap + (size_t)j * 16);
    uint4* bd = (uint4*)(Bp + (size_t)j * 16);
    ad[0] = a.v[0]; ad[1] = a.v[1];
    bd[0] = b.v[0]; bd[1] = b.v[1];
}

#define CG 8   // column groups per direction

// Block: 256 threads (4 waves). Each wave owns 64 rows (2 strips of 32).
// Block covers rows [bx*256, +256), col-group blockIdx.y (N/CG cols), dir z.
// No LDS: B fragments come straight from L2 (total B data = 1 MB, resident).
// Depth-2 prefetch: quad of tiles in flight; per-pair interleaved compute.
__global__ __launch_bounds__(256, 2) void chamfer_main(
    const unsigned short* __restrict__ ApP, const unsigned short* __restrict__ BpP,
    const unsigned short* __restrict__ ApT, const unsigned short* __restrict__ BpT,
    float* __restrict__ partials, int N)
{
    const int dir = blockIdx.z;
    const unsigned short* __restrict__ Ap = dir ? ApT : ApP;
    const unsigned short* __restrict__ Bp = dir ? BpP : BpT;
    float* __restrict__ pout = partials + (size_t)(dir * CG + blockIdx.y) * N;

    const int tid  = threadIdx.x;
    const int w    = tid >> 6;
    const int lane = tid & 63;
    const int lm   = lane & 31;     // MFMA row/col within tile
    const int lg   = lane >> 5;     // k-half (and C/D row-half)

    const int row0 = blockIdx.x * 256 + w * 64;

    // A fragments (hoisted for the whole kernel): lane needs A[row][k=lg*8..+7]
    const uint4* A4 = (const uint4*)Ap;
    s16x8 a0 = __builtin_bit_cast(s16x8, A4[(size_t)(row0      + lm) * 2 + lg]);
    s16x8 a1 = __builtin_bit_cast(s16x8, A4[(size_t)(row0 + 32 + lm) * 2 + lg]);

    float rm0[16], rm1[16];
    #pragma unroll
    for (int r = 0; r < 16; ++r) { rm0[r] = 3.0e38f; rm1[r] = 3.0e38f; }

    const f32x16 zc = {0.f,0.f,0.f,0.f,0.f,0.f,0.f,0.f,0.f,0.f,0.f,0.f,0.f,0.f,0.f,0.f};

    // This block's B slice: N/CG cols. Per-lane fragment address:
    // tile t, col lm, k-half lg -> uint4 index t*64 + lm*2 + lg (32 B/point).
    const int npt = N / CG;
    const int NT  = npt / 32;             // 64 tiles for N=16384, CG=8
    const int NQ  = NT / 4;               // 16 quads
    const uint4* bp = (const uint4*)Bp + (size_t)blockIdx.y * npt * 2 + lm * 2 + lg;

    // Quad of tiles in flight (tile stride = 64 uint4).
    uint4 c0 = bp[0], c1 = bp[64], c2 = bp[128], c3 = bp[192];
    const uint4* bn = bp + 256;

    // One PAIR of tiles: 4 MFMA + 32 fused min3, <=2 f32x16 transients.
#define PAIR(CA, CB)                                                          \
    {                                                                         \
        s16x8 bA = __builtin_bit_cast(s16x8, CA);                             \
        s16x8 bB = __builtin_bit_cast(s16x8, CB);                             \
        f32x16 p0 = __builtin_amdgcn_mfma_f32_32x32x16_bf16(a0, bA, zc, 0,0,0);\
        f32x16 q0 = __builtin_amdgcn_mfma_f32_32x32x16_bf16(a0, bB, zc, 0,0,0);\
        _Pragma("unroll")                                                     \
        for (int r = 0; r < 16; ++r)                                          \
            rm0[r] = fminf(fminf(rm0[r], p0[r]), q0[r]);                      \
        f32x16 p1 = __builtin_amdgcn_mfma_f32_32x32x16_bf16(a1, bA, zc, 0,0,0);\
        f32x16 q1 = __builtin_amdgcn_mfma_f32_32x32x16_bf16(a1, bB, zc, 0,0,0);\
        _Pragma("unroll")                                                     \
        for (int r = 0; r < 16; ++r)                                          \
            rm1[r] = fminf(fminf(rm1[r], p1[r]), q1[r]);                      \
    }

    for (int t = 0; t < NQ - 1; ++t) {
        uint4 n0 = bn[0];
        uint4 n1 = bn[64];
        PAIR(c0, c1);            // compute pair 0 while n0/n1 fly
        uint4 n2 = bn[128];
        uint4 n3 = bn[192];
        PAIR(c2, c3);            // compute pair 1 while n2/n3 fly
        bn += 256;
        c0 = n0; c1 = n1; c2 = n2; c3 = n3;
    }
    PAIR(c0, c1);                // last quad (no prefetch)
    PAIR(c2, c3);
#undef PAIR

    // Reduce row-mins across the 32 col-lanes of each half (xor stays in-half).
    #pragma unroll
    for (int m = 1; m <= 16; m <<= 1) {
        #pragma unroll
        for (int r = 0; r < 16; ++r) {
            rm0[r] = fminf(rm0[r], __shfl_xor(rm0[r], m, 64));
            rm1[r] = fminf(rm1[r], __shfl_xor(rm1[r], m, 64));
        }
    }
    // C/D layout (m74/m101): row = (r&3) + 8*(r>>2) + 4*lg, col = lane&31.
    #pragma unroll
    for (int r = 0; r < 16; ++r) {
        int rl = (r & 3) + 8 * (r >> 2) + 4 * lg;
        if (lm == r) {
            pout[row0 +      rl] = rm0[r];
            pout[row0 + 32 + rl] = rm1[r];
        }
    }
}

// Stage 1: 16 blocks x 256 threads, float4-vectorized min over the 2*CG
// partial arrays, clamp at 0, per-block double sum.
__global__ void chamfer_reduce1(const float* __restrict__ partials,
                                double* __restrict__ bsum, int N)
{
    const int n4 = N >> 2;
    const float4* p4 = (const float4*)partials;
    double acc = 0.0;
    for (int i = blockIdx.x * blockDim.x + threadIdx.x; i < n4;
         i += gridDim.x * blockDim.x) {
        float4 m0 = p4[i];
        #pragma unroll
        for (int g = 1; g < CG; ++g) {
            float4 v = p4[(size_t)g * n4 + i];
            m0.x = fminf(m0.x, v.x); m0.y = fminf(m0.y, v.y);
            m0.z = fminf(m0.z, v.z); m0.w = fminf(m0.w, v.w);
        }
        float4 m1 = p4[(size_t)CG * n4 + i];
        #pragma unroll
        for (int g = CG + 1; g < 2 * CG; ++g) {
            float4 v = p4[(size_t)g * n4 + i];
            m1.x = fminf(m1.x, v.x); m1.y = fminf(m1.y, v.y);
            m1.z = fminf(m1.z, v.z); m1.w = fminf(m1.w, v.w);
        }
        acc += (double)fmaxf(m0.x, 0.0f) + (double)fmaxf(m0.y, 0.0f)
             + (double)fmaxf(m0.z, 0.0f) + (double)fmaxf(m0.w, 0.0f)
             + (double)fmaxf(m1.x, 0.0f) + (double)fmaxf(m1.y, 0.0f)
             + (double)fmaxf(m1.z, 0.0f) + (double)fmaxf(m1.w, 0.0f);
    }
    for (int off = 32; off; off >>= 1)
        acc += __shfl_down(acc, off, 64);
    __shared__ double sacc[4];
    const int wave = threadIdx.x >> 6, lane = threadIdx.x & 63;
    if (lane == 0) sacc[wave] = acc;
    __syncthreads();
    if (threadIdx.x == 0)
        bsum[blockIdx.x] = sacc[0] + sacc[1] + sacc[2] + sacc[3];
}

// Stage 2: fold 16 block sums, write mean(dist1)+mean(dist2).
__global__ void chamfer_reduce2(const double* __restrict__ bsum,
                                float* __restrict__ out, int N, int nb)
{
    if (threadIdx.x == 0) {
        double t = 0.0;
        for (int i = 0; i < nb; ++i) t += bsum[i];
        out[0] = (float)(t / (double)N);   // N == M
    }
}

extern "C" void kernel_launch(void* const* d_in, const int* in_sizes, int n_in,
                              void* d_out, int out_size, void* d_ws, size_t ws_size,
                              hipStream_t stream) {
    const float* predict = (const float*)d_in[0];
    const float* target  = (const float*)d_in[1];
    const int N = in_sizes[0] / 3;   // 16384

    unsigned short* ws16 = (unsigned short*)d_ws;
    unsigned short* ApP = ws16;
    unsigned short* BpP = ws16 + (size_t)1 * N * 16;
    unsigned short* ApT = ws16 + (size_t)2 * N * 16;
    unsigned short* BpT = ws16 + (size_t)3 * N * 16;
    float* partials = (float*)(ws16 + (size_t)4 * N * 16);   // 2*CG*N floats
    double* bsum = (double*)(partials + (size_t)2 * CG * N); // 16 doubles

    prep_pack<<<dim3((2 * N + 255) / 256), dim3(256), 0, stream>>>(
        predict, target, ApP, BpP, ApT, BpT, N);

    dim3 grid(N / 256, CG, 2);   // 64 x 8 x 2 = 1024 blocks
    chamfer_main<<<grid, dim3(256), 0, stream>>>(ApP, BpP, ApT, BpT, partials, N);

    chamfer_reduce1<<<dim3(16), dim3(256), 0, stream>>>(partials, bsum, N);
    chamfer_reduce2<<<dim3(1), dim3(64), 0, stream>>>(bsum, (float*)d_out, N, 16);
}